// Round 1
// baseline (2390.382 us; speedup 1.0000x reference)
//
#include <hip/hip_runtime.h>
#include <hip/hip_bf16.h>
#include <math.h>

// Problem constants (BlenderbotDecoderLayer prefill)
#define TB   4
#define TS   128
#define TD   2560
#define TH   32
#define THD  80
#define TFFN 10240
#define TDEC 256
#define TM   (TB * TS)            // 512 rows
#define CACHE_N ((size_t)TB * TH * TDEC * THD)  // 2,621,440

using short8  = __attribute__((ext_vector_type(8))) short;
using floatx4 = __attribute__((ext_vector_type(4))) float;

__device__ __forceinline__ short f2bf(float f) {
  unsigned u = __builtin_bit_cast(unsigned, f);
  u += 0x7fff + ((u >> 16) & 1);           // RNE
  return (short)(u >> 16);
}
__device__ __forceinline__ float bf2f(short s) {
  unsigned u = ((unsigned)(unsigned short)s) << 16;
  return __builtin_bit_cast(float, u);
}

// ---------------------------------------------------------------------------
// GEMM: C[M,N] = A(bf16)[M,K] @ B(fp32->bf16)[K,N] + bias, epilogue variants.
// 128x128 block tile, BK=32, 4 waves in 2x2, each wave 4x4 MFMA 16x16x32.
// ---------------------------------------------------------------------------
enum { EPI_PLAIN = 0, EPI_RESID = 1, EPI_GELU = 2, EPI_SCATTER = 3 };

template<int MODE>
__global__ __launch_bounds__(256, 2)
void gemm_bf16_kernel(const short* __restrict__ A, const float* __restrict__ B,
                      const float* __restrict__ bias, const float* __restrict__ resid,
                      float* __restrict__ outf, short* __restrict__ outb,
                      int M, int N, int K)
{
  constexpr int BM = 128, BN = 128, BK = 32, LDST = 40;  // 80B row stride (16B-mult)
  __shared__ short As[BM * LDST];
  __shared__ short Bs[BN * LDST];   // stores B transposed: Bs[n][k]

  const int tid = threadIdx.x;
  const int m0 = blockIdx.y * BM;
  const int n0 = blockIdx.x * BN;
  const int lane = tid & 63;
  const int wv = tid >> 6;
  const int wm = (wv >> 1) * 64;
  const int wn = (wv & 1) * 64;
  const int lr = lane & 15;   // m (A) / n (B) / col (D)
  const int lq = lane >> 4;   // k-quad (A,B) / row-quad (D)

  floatx4 acc[4][4];
#pragma unroll
  for (int i = 0; i < 4; ++i)
#pragma unroll
    for (int j = 0; j < 4; ++j)
      acc[i][j] = floatx4{0.f, 0.f, 0.f, 0.f};

  for (int k0 = 0; k0 < K; k0 += BK) {
    // Stage A tile: 128x32 bf16, 16 elems/thread as 2x short8
#pragma unroll
    for (int it = 0; it < 2; ++it) {
      int li = (tid + it * 256) * 8;
      int r = li >> 5, c = li & 31;
      short8 av = *(const short8*)(A + (size_t)(m0 + r) * K + k0 + c);
      *(short8*)(&As[r * LDST + c]) = av;
    }
    // Stage B tile: 32x128 fp32 -> bf16 transposed, 16 elems/thread as 4x float4
#pragma unroll
    for (int it = 0; it < 4; ++it) {
      int li = (tid + it * 256) * 4;
      int kk = li >> 7, c = li & 127;
      const float4 bv = *(const float4*)(B + (size_t)(k0 + kk) * N + n0 + c);
      Bs[(c + 0) * LDST + kk] = f2bf(bv.x);
      Bs[(c + 1) * LDST + kk] = f2bf(bv.y);
      Bs[(c + 2) * LDST + kk] = f2bf(bv.z);
      Bs[(c + 3) * LDST + kk] = f2bf(bv.w);
    }
    __syncthreads();

    short8 af[4], bfr[4];
#pragma unroll
    for (int t = 0; t < 4; ++t)
      af[t] = *(const short8*)(&As[(wm + t * 16 + lr) * LDST + lq * 8]);
#pragma unroll
    for (int t = 0; t < 4; ++t)
      bfr[t] = *(const short8*)(&Bs[(wn + t * 16 + lr) * LDST + lq * 8]);
#pragma unroll
    for (int tm = 0; tm < 4; ++tm)
#pragma unroll
      for (int tn = 0; tn < 4; ++tn)
        acc[tm][tn] = __builtin_amdgcn_mfma_f32_16x16x32_bf16(af[tm], bfr[tn],
                                                              acc[tm][tn], 0, 0, 0);
    __syncthreads();
  }

  // Epilogue
#pragma unroll
  for (int tm = 0; tm < 4; ++tm) {
#pragma unroll
    for (int tn = 0; tn < 4; ++tn) {
      const int col = n0 + wn + tn * 16 + lr;
      const float bv = bias[col];
      int hh = 0, hd = 0;
      if (MODE == EPI_SCATTER) { hh = col / THD; hd = col % THD; }
#pragma unroll
      for (int r = 0; r < 4; ++r) {
        const int row = m0 + wm + tm * 16 + lq * 4 + r;
        float v = acc[tm][tn][r] + bv;
        if (MODE == EPI_PLAIN) {
          outf[(size_t)row * N + col] = v;
        } else if (MODE == EPI_RESID) {
          outf[(size_t)row * N + col] = v + resid[(size_t)row * N + col];
        } else if (MODE == EPI_GELU) {
          float g = 0.5f * v * (1.0f + erff(v * 0.70710678118654752f));
          outb[(size_t)row * N + col] = f2bf(g);
        } else {  // EPI_SCATTER: row=(b,s), col=(h,hd) -> cache[b,h,s,hd]
          int b = row >> 7, s = row & 127;
          outf[(((size_t)b * TH + hh) * TDEC + s) * THD + hd] = v;
        }
      }
    }
  }
}

// ---------------------------------------------------------------------------
// Attention: one block per (b,h, 64-q-row tile). K/V bf16 in LDS, scores in
// registers (4 lanes per q-row), softmax via shfl, P bf16 reusing Q LDS.
// ---------------------------------------------------------------------------
template<bool CAUSAL>
__global__ __launch_bounds__(256, 2)
void attn_kernel(const float* __restrict__ q, const float* __restrict__ kc,
                 const float* __restrict__ vc, short* __restrict__ ob)
{
  __shared__ short kb[TS * THD];   // 20480 B
  __shared__ short vb[TS * THD];   // 20480 B
  __shared__ float qf[64 * 84];    // 21504 B (padded stride 84); aliased by pb
  short* pb = (short*)qf;          // 64*128 shorts = 16384 B

  const int tid = threadIdx.x;
  const int bh = blockIdx.x;       // b*32 + h
  const int b = bh >> 5, h = bh & 31;
  const int r0 = blockIdx.y * 64;

  const size_t cbase = (size_t)bh * TDEC * THD;  // cache rows s<128 are prefix
  for (int idx = tid; idx < TS * THD; idx += 256) {
    kb[idx] = f2bf(kc[cbase + idx]);
    vb[idx] = f2bf(vc[cbase + idx]);
  }
  for (int idx = tid; idx < 64 * THD; idx += 256) {
    int r = idx / THD, d = idx - r * THD;
    qf[r * 84 + d] = q[(size_t)(b * TS + r0 + r) * TD + h * THD + d];
  }
  __syncthreads();

  const int r = tid >> 2;
  const int quarter = tid & 3;
  const int qi = r0 + r;

  float sc[32];
#pragma unroll 1
  for (int jj = 0; jj < 32; ++jj) {
    int j = quarter + jj * 4;                   // interleaved -> bank-spread
    if (CAUSAL && j > qi) { sc[jj] = -1e30f; continue; }
    float a = 0.f;
#pragma unroll 8
    for (int d = 0; d < THD; ++d)
      a += qf[r * 84 + d] * bf2f(kb[j * THD + d]);
    sc[jj] = a * 0.11180339887498949f;          // 1/sqrt(80)
  }

  float mx = -1e30f;
#pragma unroll
  for (int jj = 0; jj < 32; ++jj) mx = fmaxf(mx, sc[jj]);
  mx = fmaxf(mx, __shfl_xor(mx, 1));
  mx = fmaxf(mx, __shfl_xor(mx, 2));
  float sum = 0.f;
#pragma unroll
  for (int jj = 0; jj < 32; ++jj) { sc[jj] = __expf(sc[jj] - mx); sum += sc[jj]; }
  sum += __shfl_xor(sum, 1);
  sum += __shfl_xor(sum, 2);
  const float rinv = 1.0f / sum;

  __syncthreads();  // qf dead; safe to overwrite with pb
#pragma unroll
  for (int jj = 0; jj < 32; ++jj)
    pb[r * TS + quarter + jj * 4] = f2bf(sc[jj] * rinv);
  __syncthreads();

  // O = P @ V ; 5120 outputs, 20 per thread
  for (int it = 0; it < 20; ++it) {
    int idx = tid + it * 256;
    int rr = idx / THD, d = idx - rr * THD;
    float a = 0.f;
#pragma unroll 8
    for (int j = 0; j < TS; ++j)
      a += bf2f(pb[rr * TS + j]) * bf2f(vb[j * THD + d]);
    ob[(size_t)(b * TS + r0 + rr) * TD + h * THD + d] = f2bf(a);
  }
}

// ---------------------------------------------------------------------------
// Row LayerNorm -> bf16
// ---------------------------------------------------------------------------
__global__ __launch_bounds__(256, 4)
void ln_kernel(const float* __restrict__ x, const float* __restrict__ g,
               const float* __restrict__ bb, short* __restrict__ out)
{
  const int row = blockIdx.x;
  const float* xr = x + (size_t)row * TD;
  const int tid = threadIdx.x;
  float s = 0.f, ss = 0.f;
  for (int i = tid; i < TD; i += 256) { float v = xr[i]; s += v; ss += v * v; }
#pragma unroll
  for (int o = 32; o > 0; o >>= 1) { s += __shfl_xor(s, o); ss += __shfl_xor(ss, o); }
  __shared__ float red[8];
  const int wv = tid >> 6, lane = tid & 63;
  if (lane == 0) { red[wv] = s; red[wv + 4] = ss; }
  __syncthreads();
  s  = red[0] + red[1] + red[2] + red[3];
  ss = red[4] + red[5] + red[6] + red[7];
  const float mu = s * (1.0f / TD);
  const float var = ss * (1.0f / TD) - mu * mu;
  const float rstd = rsqrtf(var + 1e-5f);
  short* orow = out + (size_t)row * TD;
  for (int i = tid; i < TD; i += 256)
    orow[i] = f2bf((xr[i] - mu) * rstd * g[i] + bb[i]);
}

__global__ void cvt_bf16_kernel(const float* __restrict__ in, short* __restrict__ out, int n)
{
  int i = blockIdx.x * 256 + threadIdx.x;
  if (i < n) out[i] = f2bf(in[i]);
}

// Copy cache tail rows (s in [128,256)) from input cache to output cache.
// grid = (10, B*H); float4 granularity.
__global__ void tailcopy_kernel(const float* __restrict__ src, float* __restrict__ dst)
{
  int off4 = blockIdx.x * 256 + threadIdx.x;     // 0..2559 (float4 units)
  int chunk = blockIdx.y;                        // (b,h)
  size_t pos = (size_t)chunk * 5120 + 2560 + off4;
  ((float4*)dst)[pos] = ((const float4*)src)[pos];
}

// ---------------------------------------------------------------------------
extern "C" void kernel_launch(void* const* d_in, const int* in_sizes, int n_in,
                              void* d_out, int out_size, void* d_ws, size_t ws_size,
                              hipStream_t stream)
{
  (void)in_sizes; (void)n_in; (void)out_size; (void)ws_size;
  const float* x        = (const float*)d_in[0];
  const float* xa       = (const float*)d_in[1];
  // d_in[2], d_in[3]: masks — compile-time known (causal over 128 / first 128)
  const float* ln1_g    = (const float*)d_in[4];
  const float* ln1_b    = (const float*)d_in[5];
  const float* ln2_g    = (const float*)d_in[6];
  const float* ln2_b    = (const float*)d_in[7];
  const float* ln3_g    = (const float*)d_in[8];
  const float* ln3_b    = (const float*)d_in[9];
  const float* sa_wq    = (const float*)d_in[10];
  const float* sa_wk    = (const float*)d_in[11];
  const float* sa_wv    = (const float*)d_in[12];
  const float* sa_wo    = (const float*)d_in[13];
  const float* sa_bq    = (const float*)d_in[14];
  const float* sa_bk    = (const float*)d_in[15];
  const float* sa_bv    = (const float*)d_in[16];
  const float* sa_bo    = (const float*)d_in[17];
  const float* ca_wq    = (const float*)d_in[18];
  const float* ca_wk    = (const float*)d_in[19];
  const float* ca_wv    = (const float*)d_in[20];
  const float* ca_wo    = (const float*)d_in[21];
  const float* ca_bq    = (const float*)d_in[22];
  const float* ca_bk    = (const float*)d_in[23];
  const float* ca_bv    = (const float*)d_in[24];
  const float* ca_bo    = (const float*)d_in[25];
  const float* cache_sk = (const float*)d_in[26];
  const float* cache_sv = (const float*)d_in[27];
  const float* cache_ck = (const float*)d_in[28];
  const float* cache_cv = (const float*)d_in[29];
  const float* fc1_w    = (const float*)d_in[30];
  const float* fc1_b    = (const float*)d_in[31];
  const float* fc2_w    = (const float*)d_in[32];
  const float* fc2_b    = (const float*)d_in[33];

  float* out_x  = (float*)d_out;
  float* out_sk = out_x + (size_t)TM * TD;
  float* out_sv = out_sk + CACHE_N;
  float* out_ck = out_sv + CACHE_N;
  float* out_cv = out_ck + CACHE_N;

  char* w = (char*)d_ws;
  short* h_b   = (short*)w; w += (size_t)TM * TD * 2;
  short* xa_b  = (short*)w; w += (size_t)TM * TD * 2;
  short* o_b   = (short*)w; w += (size_t)TM * TD * 2;
  short* ffn_b = (short*)w; w += (size_t)TM * TFFN * 2;
  float* qbuf  = (float*)w; w += (size_t)TM * TD * 4;
  float* x1    = (float*)w; w += (size_t)TM * TD * 4;
  float* x2    = (float*)w; w += (size_t)TM * TD * 4;

  const dim3 blk(256);
  const dim3 gD(TD / 128, TM / 128);     // (20, 4)  D x D GEMMs
  const dim3 gF1(TFFN / 128, TM / 128);  // (80, 4)  fc1
  const dim3 gAttn(TB * TH, 2);          // (128, 2)

  // prep
  cvt_bf16_kernel<<<dim3(TM * TD / 256), blk, 0, stream>>>(xa, xa_b, TM * TD);
  tailcopy_kernel<<<dim3(10, TB * TH), blk, 0, stream>>>(cache_sk, out_sk);
  tailcopy_kernel<<<dim3(10, TB * TH), blk, 0, stream>>>(cache_sv, out_sv);
  tailcopy_kernel<<<dim3(10, TB * TH), blk, 0, stream>>>(cache_ck, out_ck);
  tailcopy_kernel<<<dim3(10, TB * TH), blk, 0, stream>>>(cache_cv, out_cv);

  // ---- self-attention ----
  ln_kernel<<<dim3(TM), blk, 0, stream>>>(x, ln1_g, ln1_b, h_b);
  gemm_bf16_kernel<EPI_PLAIN><<<gD, blk, 0, stream>>>(h_b, sa_wq, sa_bq, nullptr,
                                                      qbuf, nullptr, TM, TD, TD);
  gemm_bf16_kernel<EPI_SCATTER><<<gD, blk, 0, stream>>>(h_b, sa_wk, sa_bk, nullptr,
                                                        out_sk, nullptr, TM, TD, TD);
  gemm_bf16_kernel<EPI_SCATTER><<<gD, blk, 0, stream>>>(h_b, sa_wv, sa_bv, nullptr,
                                                        out_sv, nullptr, TM, TD, TD);
  attn_kernel<true><<<gAttn, blk, 0, stream>>>(qbuf, out_sk, out_sv, o_b);
  gemm_bf16_kernel<EPI_RESID><<<gD, blk, 0, stream>>>(o_b, sa_wo, sa_bo, x,
                                                      x1, nullptr, TM, TD, TD);

  // ---- cross-attention ----
  ln_kernel<<<dim3(TM), blk, 0, stream>>>(x1, ln2_g, ln2_b, h_b);
  gemm_bf16_kernel<EPI_PLAIN><<<gD, blk, 0, stream>>>(h_b, ca_wq, ca_bq, nullptr,
                                                      qbuf, nullptr, TM, TD, TD);
  gemm_bf16_kernel<EPI_SCATTER><<<gD, blk, 0, stream>>>(xa_b, ca_wk, ca_bk, nullptr,
                                                        out_ck, nullptr, TM, TD, TD);
  gemm_bf16_kernel<EPI_SCATTER><<<gD, blk, 0, stream>>>(xa_b, ca_wv, ca_bv, nullptr,
                                                        out_cv, nullptr, TM, TD, TD);
  attn_kernel<false><<<gAttn, blk, 0, stream>>>(qbuf, out_ck, out_cv, o_b);
  gemm_bf16_kernel<EPI_RESID><<<gD, blk, 0, stream>>>(o_b, ca_wo, ca_bo, x1,
                                                      x2, nullptr, TM, TD, TD);

  // ---- MLP ----
  ln_kernel<<<dim3(TM), blk, 0, stream>>>(x2, ln3_g, ln3_b, h_b);
  gemm_bf16_kernel<EPI_GELU><<<gF1, blk, 0, stream>>>(h_b, fc1_w, fc1_b, nullptr,
                                                      nullptr, ffn_b, TM, TFFN, TD);
  gemm_bf16_kernel<EPI_RESID><<<gD, blk, 0, stream>>>(ffn_b, fc2_w, fc2_b, x2,
                                                      out_x, nullptr, TM, TD, TFFN);
}

// Round 2
// 996.391 us; speedup vs baseline: 2.3990x; 2.3990x over previous
//
#include <hip/hip_runtime.h>
#include <hip/hip_bf16.h>
#include <math.h>

// Problem constants (BlenderbotDecoderLayer prefill)
#define TB   4
#define TS   128
#define TD   2560
#define TH   32
#define THD  80
#define TFFN 10240
#define TDEC 256
#define TM   (TB * TS)            // 512 rows
#define CACHE_N ((size_t)TB * TH * TDEC * THD)  // 2,621,440

using short8  = __attribute__((ext_vector_type(8))) short;
using floatx4 = __attribute__((ext_vector_type(4))) float;

__device__ __forceinline__ short f2bf(float f) {
  unsigned u = __builtin_bit_cast(unsigned, f);
  u += 0x7fff + ((u >> 16) & 1);           // RNE
  return (short)(u >> 16);
}
__device__ __forceinline__ float bf2f(short s) {
  unsigned u = ((unsigned)(unsigned short)s) << 16;
  return __builtin_bit_cast(float, u);
}

// ---------------------------------------------------------------------------
// Fused multi-segment GEMM with register double-buffering.
//   C[M,N] = A(bf16)[M,K] @ B(fp32, [K,N])   (+bias, epilogue per segment)
// 128x128 tile, BK=32, 4 waves 2x2, wave = 4x4 MFMA 16x16x32_bf16.
// blockIdx.x = seg*tilesPerSeg + n-tile; blockIdx.y = m-tile; blockIdx.z = k-chunk.
// LDS rows padded to 40 shorts (80 B): staging writes hit bank-quad
// (5*row + chunk) mod 8 (5 coprime 8 -> balanced, conflict-free).
// ---------------------------------------------------------------------------
enum { EPI_PLAIN = 0, EPI_GELU = 2, EPI_SCATTER = 3 };

struct GArgs {
  const short* A[3];
  const float* B[3];
  const float* bias[3];   // nullable
  float*       outf[3];
  short*       outb[3];
  int          mode[3];
  int tilesPerSeg;
  int N;      // columns per segment
  int lda;    // full K of A
  int Kc;     // K-chunk per blockIdx.z
};

__device__ __forceinline__ void stage_load(const short* __restrict__ A,
                                           const float* __restrict__ B,
                                           int lda, int N, int m0, int n0, int k0,
                                           int tid, short8 ra[2], float rb[16])
{
  const int cb = (tid & 3) * 8;
  const int rr = tid >> 2;
#pragma unroll
  for (int it = 0; it < 2; ++it)
    ra[it] = *(const short8*)(A + (size_t)(m0 + rr + it * 64) * lda + k0 + cb);
  const int n  = tid & 127;
  const int kg = (tid >> 7) * 16;
  const float* bp = B + (size_t)(k0 + kg) * N + n0 + n;
#pragma unroll
  for (int j = 0; j < 16; ++j)
    rb[j] = bp[(size_t)j * N];
}

__device__ __forceinline__ void stage_commit(short* __restrict__ As, short* __restrict__ Bs,
                                             int tid, const short8 ra[2], const float rb[16])
{
  const int cb = (tid & 3) * 8;
  const int rr = tid >> 2;
#pragma unroll
  for (int it = 0; it < 2; ++it)
    *(short8*)(&As[(rr + it * 64) * 40 + cb]) = ra[it];
  const int n  = tid & 127;
  const int kg = (tid >> 7) * 16;
  short8 lo, hi;
#pragma unroll
  for (int j = 0; j < 8; ++j) { lo[j] = f2bf(rb[j]); hi[j] = f2bf(rb[8 + j]); }
  *(short8*)(&Bs[n * 40 + kg])     = lo;
  *(short8*)(&Bs[n * 40 + kg + 8]) = hi;
}

__global__ __launch_bounds__(256, 2)
void gemmF(GArgs g)
{
  __shared__ short As[2][128 * 40];   // 10240 B each
  __shared__ short Bs[2][128 * 40];   // total 40960 B

  const int seg = blockIdx.x / g.tilesPerSeg;
  const int tx  = blockIdx.x % g.tilesPerSeg;
  const short* A = g.A[seg];
  const float* B = g.B[seg];
  const int N = g.N, lda = g.lda;
  const int m0 = blockIdx.y * 128;
  const int n0 = tx * 128;
  const int z  = blockIdx.z;
  const int k0base = z * g.Kc;
  const int nk = g.Kc / 32;

  const int tid = threadIdx.x;
  const int lane = tid & 63;
  const int wv = tid >> 6;
  const int wm = (wv >> 1) * 64;
  const int wn = (wv & 1) * 64;
  const int lr = lane & 15;
  const int lq = lane >> 4;

  floatx4 acc[4][4];
#pragma unroll
  for (int i = 0; i < 4; ++i)
#pragma unroll
    for (int j = 0; j < 4; ++j)
      acc[i][j] = floatx4{0.f, 0.f, 0.f, 0.f};

  short8 ra[2]; float rb[16];
  stage_load(A, B, lda, N, m0, n0, k0base, tid, ra, rb);
  stage_commit(As[0], Bs[0], tid, ra, rb);
  __syncthreads();

  for (int ki = 0; ki < nk; ++ki) {
    const int cur = ki & 1;
    const bool more = (ki + 1 < nk);
    if (more)
      stage_load(A, B, lda, N, m0, n0, k0base + (ki + 1) * 32, tid, ra, rb);

    short8 af[4], bfr[4];
#pragma unroll
    for (int t = 0; t < 4; ++t)
      af[t] = *(const short8*)(&As[cur][(wm + t * 16 + lr) * 40 + lq * 8]);
#pragma unroll
    for (int t = 0; t < 4; ++t)
      bfr[t] = *(const short8*)(&Bs[cur][(wn + t * 16 + lr) * 40 + lq * 8]);
#pragma unroll
    for (int tm = 0; tm < 4; ++tm)
#pragma unroll
      for (int tn = 0; tn < 4; ++tn)
        acc[tm][tn] = __builtin_amdgcn_mfma_f32_16x16x32_bf16(af[tm], bfr[tn],
                                                              acc[tm][tn], 0, 0, 0);
    if (more)
      stage_commit(As[cur ^ 1], Bs[cur ^ 1], tid, ra, rb);
    __syncthreads();
  }

  // Epilogue
  const float* bias = g.bias[seg];
  float* outf = g.outf[seg];
  short* outb = g.outb[seg];
  const int mode = g.mode[seg];
#pragma unroll
  for (int tm = 0; tm < 4; ++tm) {
#pragma unroll
    for (int tn = 0; tn < 4; ++tn) {
      const int col = n0 + wn + tn * 16 + lr;
      const float bv = bias ? bias[col] : 0.f;
      int hh = 0, hd = 0;
      if (mode == EPI_SCATTER) { hh = col / THD; hd = col % THD; }
#pragma unroll
      for (int r = 0; r < 4; ++r) {
        const int row = m0 + wm + tm * 16 + lq * 4 + r;
        float v = acc[tm][tn][r] + bv;
        if (mode == EPI_PLAIN) {
          outf[(size_t)z * TM * N + (size_t)row * N + col] = v;
        } else if (mode == EPI_GELU) {
          float gg = 0.5f * v * (1.0f + erff(v * 0.70710678118654752f));
          outb[(size_t)row * N + col] = f2bf(gg);
        } else {  // EPI_SCATTER: row=(b,s), col=(h,hd) -> cache[b,h,s,hd]
          int b = row >> 7, s = row & 127;
          outf[(((size_t)b * TH + hh) * TDEC + s) * THD + hd] = v;
        }
      }
    }
  }
}

// ---------------------------------------------------------------------------
// Attention: one block per (b,h, 64-q-row tile). K/V bf16 in LDS, scores in
// registers (4 lanes per q-row), softmax via shfl, P bf16 reusing Q LDS.
// ---------------------------------------------------------------------------
template<bool CAUSAL>
__global__ __launch_bounds__(256, 2)
void attn_kernel(const float* __restrict__ q, const float* __restrict__ kc,
                 const float* __restrict__ vc, short* __restrict__ ob)
{
  __shared__ short kb[TS * THD];
  __shared__ short vb[TS * THD];
  __shared__ float qf[64 * 84];
  short* pb = (short*)qf;

  const int tid = threadIdx.x;
  const int bh = blockIdx.x;
  const int b = bh >> 5, h = bh & 31;
  const int r0 = blockIdx.y * 64;

  const size_t cbase = (size_t)bh * TDEC * THD;
  for (int idx = tid; idx < TS * THD; idx += 256) {
    kb[idx] = f2bf(kc[cbase + idx]);
    vb[idx] = f2bf(vc[cbase + idx]);
  }
  for (int idx = tid; idx < 64 * THD; idx += 256) {
    int r = idx / THD, d = idx - r * THD;
    qf[r * 84 + d] = q[(size_t)(b * TS + r0 + r) * TD + h * THD + d];
  }
  __syncthreads();

  const int r = tid >> 2;
  const int quarter = tid & 3;
  const int qi = r0 + r;

  float sc[32];
#pragma unroll 1
  for (int jj = 0; jj < 32; ++jj) {
    int j = quarter + jj * 4;
    if (CAUSAL && j > qi) { sc[jj] = -1e30f; continue; }
    float a = 0.f;
#pragma unroll 8
    for (int d = 0; d < THD; ++d)
      a += qf[r * 84 + d] * bf2f(kb[j * THD + d]);
    sc[jj] = a * 0.11180339887498949f;
  }

  float mx = -1e30f;
#pragma unroll
  for (int jj = 0; jj < 32; ++jj) mx = fmaxf(mx, sc[jj]);
  mx = fmaxf(mx, __shfl_xor(mx, 1));
  mx = fmaxf(mx, __shfl_xor(mx, 2));
  float sum = 0.f;
#pragma unroll
  for (int jj = 0; jj < 32; ++jj) { sc[jj] = __expf(sc[jj] - mx); sum += sc[jj]; }
  sum += __shfl_xor(sum, 1);
  sum += __shfl_xor(sum, 2);
  const float rinv = 1.0f / sum;

  __syncthreads();
#pragma unroll
  for (int jj = 0; jj < 32; ++jj)
    pb[r * TS + quarter + jj * 4] = f2bf(sc[jj] * rinv);
  __syncthreads();

  for (int it = 0; it < 20; ++it) {
    int idx = tid + it * 256;
    int rr = idx / THD, d = idx - rr * THD;
    float a = 0.f;
#pragma unroll 8
    for (int j = 0; j < TS; ++j)
      a += bf2f(pb[rr * TS + j]) * bf2f(vb[j * THD + d]);
    ob[(size_t)(b * TS + r0 + rr) * TD + h * THD + d] = f2bf(a);
  }
}

// ---------------------------------------------------------------------------
// LayerNorm variants
// ---------------------------------------------------------------------------
__global__ __launch_bounds__(256, 4)
void ln_kernel(const float* __restrict__ x, const float* __restrict__ g,
               const float* __restrict__ bb, short* __restrict__ out)
{
  const int row = blockIdx.x;
  const float* xr = x + (size_t)row * TD;
  const int tid = threadIdx.x;
  float vals[10];
  float s = 0.f, ss = 0.f;
#pragma unroll
  for (int it = 0; it < 10; ++it) {
    float v = xr[tid + it * 256];
    vals[it] = v; s += v; ss += v * v;
  }
#pragma unroll
  for (int o = 32; o > 0; o >>= 1) { s += __shfl_xor(s, o); ss += __shfl_xor(ss, o); }
  __shared__ float red[8];
  const int wv = tid >> 6, lane = tid & 63;
  if (lane == 0) { red[wv] = s; red[wv + 4] = ss; }
  __syncthreads();
  s  = red[0] + red[1] + red[2] + red[3];
  ss = red[4] + red[5] + red[6] + red[7];
  const float mu = s * (1.0f / TD);
  const float rstd = rsqrtf(ss * (1.0f / TD) - mu * mu + 1e-5f);
  short* orow = out + (size_t)row * TD;
#pragma unroll
  for (int it = 0; it < 10; ++it) {
    int i = tid + it * 256;
    orow[i] = f2bf((vals[it] - mu) * rstd * g[i] + bb[i]);
  }
}

// x_next = xin + p0 + p1 + obias; write x_next (fp32) and LN(x_next) (bf16)
__global__ __launch_bounds__(256, 4)
void ln_fuse_kernel(const float* __restrict__ xin, const float* __restrict__ p,
                    const float* __restrict__ obias,
                    const float* __restrict__ g, const float* __restrict__ bb,
                    short* __restrict__ hout, float* __restrict__ xout)
{
  const int row = blockIdx.x;
  const int tid = threadIdx.x;
  const size_t base = (size_t)row * TD;
  const float* p0 = p;
  const float* p1 = p + (size_t)TM * TD;
  float vals[10];
  float s = 0.f, ss = 0.f;
#pragma unroll
  for (int it = 0; it < 10; ++it) {
    int i = tid + it * 256;
    float v = xin[base + i] + p0[base + i] + p1[base + i] + obias[i];
    vals[it] = v; xout[base + i] = v; s += v; ss += v * v;
  }
#pragma unroll
  for (int o = 32; o > 0; o >>= 1) { s += __shfl_xor(s, o); ss += __shfl_xor(ss, o); }
  __shared__ float red[8];
  const int wv = tid >> 6, lane = tid & 63;
  if (lane == 0) { red[wv] = s; red[wv + 4] = ss; }
  __syncthreads();
  s  = red[0] + red[1] + red[2] + red[3];
  ss = red[4] + red[5] + red[6] + red[7];
  const float mu = s * (1.0f / TD);
  const float rstd = rsqrtf(ss * (1.0f / TD) - mu * mu + 1e-5f);
#pragma unroll
  for (int it = 0; it < 10; ++it) {
    int i = tid + it * 256;
    hout[base + i] = f2bf((vals[it] - mu) * rstd * g[i] + bb[i]);
  }
}

// out = x2 + p0+p1+p2+p3 + bias
__global__ void fc2_combine_kernel(const float* __restrict__ x2, const float* __restrict__ p,
                                   const float* __restrict__ bias, float* __restrict__ out)
{
  const size_t i = (size_t)blockIdx.x * 256 + threadIdx.x;
  const int col = (int)(i % TD);
  const size_t S1 = (size_t)TM * TD;
  out[i] = x2[i] + p[i] + p[i + S1] + p[i + 2 * S1] + p[i + 3 * S1] + bias[col];
}

__global__ void cvt_bf16_kernel(const float* __restrict__ in, short* __restrict__ out, int n)
{
  int i = blockIdx.x * 256 + threadIdx.x;
  if (i < n) out[i] = f2bf(in[i]);
}

// Copy cache tail rows (s in [128,256)); float4 granularity.
__global__ void tailcopy_kernel(const float* __restrict__ src, float* __restrict__ dst)
{
  int off4 = blockIdx.x * 256 + threadIdx.x;
  int chunk = blockIdx.y;
  size_t pos = (size_t)chunk * 5120 + 2560 + off4;
  ((float4*)dst)[pos] = ((const float4*)src)[pos];
}

// ---------------------------------------------------------------------------
extern "C" void kernel_launch(void* const* d_in, const int* in_sizes, int n_in,
                              void* d_out, int out_size, void* d_ws, size_t ws_size,
                              hipStream_t stream)
{
  (void)in_sizes; (void)n_in; (void)out_size; (void)ws_size;
  const float* x        = (const float*)d_in[0];
  const float* xa       = (const float*)d_in[1];
  const float* ln1_g    = (const float*)d_in[4];
  const float* ln1_b    = (const float*)d_in[5];
  const float* ln2_g    = (const float*)d_in[6];
  const float* ln2_b    = (const float*)d_in[7];
  const float* ln3_g    = (const float*)d_in[8];
  const float* ln3_b    = (const float*)d_in[9];
  const float* sa_wq    = (const float*)d_in[10];
  const float* sa_wk    = (const float*)d_in[11];
  const float* sa_wv    = (const float*)d_in[12];
  const float* sa_wo    = (const float*)d_in[13];
  const float* sa_bq    = (const float*)d_in[14];
  const float* sa_bk    = (const float*)d_in[15];
  const float* sa_bv    = (const float*)d_in[16];
  const float* sa_bo    = (const float*)d_in[17];
  const float* ca_wq    = (const float*)d_in[18];
  const float* ca_wk    = (const float*)d_in[19];
  const float* ca_wv    = (const float*)d_in[20];
  const float* ca_wo    = (const float*)d_in[21];
  const float* ca_bq    = (const float*)d_in[22];
  const float* ca_bk    = (const float*)d_in[23];
  const float* ca_bv    = (const float*)d_in[24];
  const float* ca_bo    = (const float*)d_in[25];
  const float* cache_sk = (const float*)d_in[26];
  const float* cache_sv = (const float*)d_in[27];
  const float* cache_ck = (const float*)d_in[28];
  const float* cache_cv = (const float*)d_in[29];
  const float* fc1_w    = (const float*)d_in[30];
  const float* fc1_b    = (const float*)d_in[31];
  const float* fc2_w    = (const float*)d_in[32];
  const float* fc2_b    = (const float*)d_in[33];

  float* out_x  = (float*)d_out;
  float* out_sk = out_x + (size_t)TM * TD;
  float* out_sv = out_sk + CACHE_N;
  float* out_ck = out_sv + CACHE_N;
  float* out_cv = out_ck + CACHE_N;

  char* w = (char*)d_ws;
  short* h_b   = (short*)w; w += (size_t)TM * TD * 2;
  short* xa_b  = (short*)w; w += (size_t)TM * TD * 2;
  short* o_b   = (short*)w; w += (size_t)TM * TD * 2;
  short* ffn_b = (short*)w; w += (size_t)TM * TFFN * 2;
  float* qbuf  = (float*)w; w += (size_t)TM * TD * 4;
  float* x1    = (float*)w; w += (size_t)TM * TD * 4;
  float* x2    = (float*)w; w += (size_t)TM * TD * 4;
  float* pbuf  = (float*)w; w += (size_t)TM * TD * 4 * 4;

  const dim3 blk(256);
  const dim3 gAttn(TB * TH, 2);

  // prep
  cvt_bf16_kernel<<<dim3(TM * TD / 256), blk, 0, stream>>>(xa, xa_b, TM * TD);
  tailcopy_kernel<<<dim3(10, TB * TH), blk, 0, stream>>>(cache_sk, out_sk);
  tailcopy_kernel<<<dim3(10, TB * TH), blk, 0, stream>>>(cache_sv, out_sv);
  tailcopy_kernel<<<dim3(10, TB * TH), blk, 0, stream>>>(cache_ck, out_ck);
  tailcopy_kernel<<<dim3(10, TB * TH), blk, 0, stream>>>(cache_cv, out_cv);

  // ---- self-attention ----
  ln_kernel<<<dim3(TM), blk, 0, stream>>>(x, ln1_g, ln1_b, h_b);
  {
    GArgs a{};
    a.A[0] = h_b;  a.B[0] = sa_wq; a.bias[0] = sa_bq; a.outf[0] = qbuf;   a.mode[0] = EPI_PLAIN;
    a.A[1] = h_b;  a.B[1] = sa_wk; a.bias[1] = sa_bk; a.outf[1] = out_sk; a.mode[1] = EPI_SCATTER;
    a.A[2] = h_b;  a.B[2] = sa_wv; a.bias[2] = sa_bv; a.outf[2] = out_sv; a.mode[2] = EPI_SCATTER;
    a.tilesPerSeg = 20; a.N = TD; a.lda = TD; a.Kc = TD;
    gemmF<<<dim3(60, 4, 1), blk, 0, stream>>>(a);
  }
  attn_kernel<true><<<gAttn, blk, 0, stream>>>(qbuf, out_sk, out_sv, o_b);
  {
    GArgs a{};
    a.A[0] = o_b; a.B[0] = sa_wo; a.bias[0] = nullptr; a.outf[0] = pbuf; a.mode[0] = EPI_PLAIN;
    a.tilesPerSeg = 20; a.N = TD; a.lda = TD; a.Kc = TD / 2;
    gemmF<<<dim3(20, 4, 2), blk, 0, stream>>>(a);
  }
  ln_fuse_kernel<<<dim3(TM), blk, 0, stream>>>(x, pbuf, sa_bo, ln2_g, ln2_b, h_b, x1);

  // ---- cross-attention ----
  {
    GArgs a{};
    a.A[0] = h_b;  a.B[0] = ca_wq; a.bias[0] = ca_bq; a.outf[0] = qbuf;   a.mode[0] = EPI_PLAIN;
    a.A[1] = xa_b; a.B[1] = ca_wk; a.bias[1] = ca_bk; a.outf[1] = out_ck; a.mode[1] = EPI_SCATTER;
    a.A[2] = xa_b; a.B[2] = ca_wv; a.bias[2] = ca_bv; a.outf[2] = out_cv; a.mode[2] = EPI_SCATTER;
    a.tilesPerSeg = 20; a.N = TD; a.lda = TD; a.Kc = TD;
    gemmF<<<dim3(60, 4, 1), blk, 0, stream>>>(a);
  }
  attn_kernel<false><<<gAttn, blk, 0, stream>>>(qbuf, out_ck, out_cv, o_b);
  {
    GArgs a{};
    a.A[0] = o_b; a.B[0] = ca_wo; a.bias[0] = nullptr; a.outf[0] = pbuf; a.mode[0] = EPI_PLAIN;
    a.tilesPerSeg = 20; a.N = TD; a.lda = TD; a.Kc = TD / 2;
    gemmF<<<dim3(20, 4, 2), blk, 0, stream>>>(a);
  }
  ln_fuse_kernel<<<dim3(TM), blk, 0, stream>>>(x1, pbuf, ca_bo, ln3_g, ln3_b, h_b, x2);

  // ---- MLP ----
  {
    GArgs a{};
    a.A[0] = h_b; a.B[0] = fc1_w; a.bias[0] = fc1_b; a.outb[0] = ffn_b; a.mode[0] = EPI_GELU;
    a.tilesPerSeg = 80; a.N = TFFN; a.lda = TD; a.Kc = TD;
    gemmF<<<dim3(80, 4, 1), blk, 0, stream>>>(a);
  }
  {
    GArgs a{};
    a.A[0] = ffn_b; a.B[0] = fc2_w; a.bias[0] = nullptr; a.outf[0] = pbuf; a.mode[0] = EPI_PLAIN;
    a.tilesPerSeg = 20; a.N = TD; a.lda = TFFN; a.Kc = TFFN / 4;
    gemmF<<<dim3(20, 4, 4), blk, 0, stream>>>(a);
  }
  fc2_combine_kernel<<<dim3(TM * TD / 256), blk, 0, stream>>>(x2, pbuf, fc2_b, out_x);
}